// Round 5
// baseline (608.692 us; speedup 1.0000x reference)
//
#include <hip/hip_runtime.h>
#include <hip/hip_bf16.h>

#define N_SITES 50000
#define N_PERM  12
#define N_NEIGH 8
#define NODE_F  64
#define IN_F    512
#define OUT_F   64
#define N_TILES (N_SITES / 16)   // 3125 exact
#define LN2F    0.69314718055994530942f

typedef __bf16 bf16x8 __attribute__((ext_vector_type(8)));
typedef float  f32x4  __attribute__((ext_vector_type(4)));

// ---- dtype detector: 1 = bf16 tensors, 0 = fp32 tensors -------------------
// R1-R3 forensics: fp32 data (flag=0) is the live path; keep both for safety.
__global__ void detect_dtype(const unsigned short* __restrict__ Xh,
                             int* __restrict__ flag) {
    int lane = threadIdx.x;                 // 64 threads
    unsigned short h = Xh[2 * lane];
    int e = (h >> 7) & 0xFF;
    int ok = (e >= 110 && e <= 140);
    unsigned long long mm = __ballot(ok);
    if (lane == 0) flag[0] = (__popcll(mm) >= 48) ? 1 : 0;
}

__device__ __forceinline__ unsigned short f32_to_bf16_rne(unsigned int u) {
    u += 0x7FFFu + ((u >> 16) & 1u);
    return (unsigned short)(u >> 16);
}

// ---- X fp32 -> bf16 into workspace (runs only on fp32 data) ---------------
__global__ void convert_x(const uint4* __restrict__ Xf, uint4* __restrict__ Xb,
                          const int* __restrict__ flag) {
    if (flag[0] != 0) return;
    int c = blockIdx.x * blockDim.x + threadIdx.x;   // chunk of 8 floats
    if (c >= N_SITES * NODE_F / 8) return;
    uint4 a = Xf[2 * c], b = Xf[2 * c + 1];
    uint4 o;
    o.x = (unsigned int)f32_to_bf16_rne(a.x) | ((unsigned int)f32_to_bf16_rne(a.y) << 16);
    o.y = (unsigned int)f32_to_bf16_rne(a.z) | ((unsigned int)f32_to_bf16_rne(a.w) << 16);
    o.z = (unsigned int)f32_to_bf16_rne(b.x) | ((unsigned int)f32_to_bf16_rne(b.y) << 16);
    o.w = (unsigned int)f32_to_bf16_rne(b.z) | ((unsigned int)f32_to_bf16_rne(b.w) << 16);
    Xb[c] = o;
}

__device__ __forceinline__ float softplus_sh(float x) {
    float t = __expf(-fabsf(x));
    return fmaxf(x, 0.f) + 0.69314718056f * __log2f(1.f + t);
}

// Block = 512 thr = 8 waves = 2 tile-slots x 4 perm-quarters (3 perms each).
// REGISTER DISCIPLINE (R3/R4 spilled ~170-380 MB to scratch): 1 perm per acc
// group -> AGPR side acc[4]+carry, VGPR side {sum 16, idx 8, afr 4, bfr 4,
// bias 4, addr ~20} = ~56 <= the 64-arch-VGPR half of the 128 budget that
// __launch_bounds__(512,4) implies on the unified gfx950 file.
// W (64x512 bf16) in LDS, rows rotated 8*o halves -> conflict-free.
// Quarter partials merge through a 26 KB buffer ALIASED onto ldsW
// (barrier-separated); total LDS 64 KiB -> 2 blocks/CU = 16 waves/CU.
template<int IS_BF16, int A_BF16>
__global__ __launch_bounds__(512, 4)
void lcnn_main(const void* __restrict__ Asrc, const int* __restrict__ NS,
               const void* __restrict__ Wv, const void* __restrict__ Bv,
               void* __restrict__ outv, const int* __restrict__ flag)
{
    if (flag[0] != IS_BF16) return;         // block-uniform, before any barrier

    __shared__ __bf16 ldsW[OUT_F * IN_F];   // 64 KiB

    #pragma unroll
    for (int it = 0; it < 8; ++it) {
        int c   = it * 512 + threadIdx.x;   // chunk of 8 halves
        int o   = c >> 6;
        int kc  = (c & 63) << 3;
        int dst = o * IN_F + ((kc + 8 * o) & (IN_F - 1));
        if (IS_BF16) {
            *(uint4*)(&ldsW[dst]) = ((const uint4*)Wv)[c];
        } else {
            uint4 a = ((const uint4*)Wv)[2 * c];
            uint4 b = ((const uint4*)Wv)[2 * c + 1];
            uint4 o4;
            o4.x = (unsigned int)f32_to_bf16_rne(a.x) | ((unsigned int)f32_to_bf16_rne(a.y) << 16);
            o4.y = (unsigned int)f32_to_bf16_rne(a.z) | ((unsigned int)f32_to_bf16_rne(a.w) << 16);
            o4.z = (unsigned int)f32_to_bf16_rne(b.x) | ((unsigned int)f32_to_bf16_rne(b.y) << 16);
            o4.w = (unsigned int)f32_to_bf16_rne(b.z) | ((unsigned int)f32_to_bf16_rne(b.w) << 16);
            *(uint4*)(&ldsW[dst]) = o4;
        }
    }
    __syncthreads();

    const int wave  = threadIdx.x >> 6;
    const int lane  = threadIdx.x & 63;
    const int tslot = wave >> 2;            // tile slot in block (0..1)
    const int q     = wave & 3;             // perm quarter (3 perms each)
    const int tile  = blockIdx.x * 2 + tslot;
    const bool active = (tile < N_TILES);

    const int m    = lane & 15;
    const int quad = lane >> 4;
    const int site = tile * 16 + m;

    f32x4 sum[4];
    #pragma unroll
    for (int nb = 0; nb < 4; ++nb) sum[nb] = (f32x4){0.f, 0.f, 0.f, 0.f};
    float bias[4] = {0.f, 0.f, 0.f, 0.f};

    if (active) {
        #pragma unroll
        for (int nb = 0; nb < 4; ++nb) {
            int i = nb * 16 + m;
            bias[nb] = IS_BF16 ? (float)((const __bf16*)Bv)[i] : ((const float*)Bv)[i];
        }
        const int4* nsbase = (const int4*)(NS + (size_t)site * (N_PERM * N_NEIGH));

        for (int j = 0; j < 3; ++j) {       // one perm at a time
            const int p = q * 3 + j;
            int idx[8];
            {
                int4 a0 = nsbase[p * 2];
                int4 a1 = nsbase[p * 2 + 1];
                idx[0] = a0.x; idx[1] = a0.y; idx[2] = a0.z; idx[3] = a0.w;
                idx[4] = a1.x; idx[5] = a1.y; idx[6] = a1.z; idx[7] = a1.w;
            }

            f32x4 acc[4];
            #pragma unroll
            for (int nb = 0; nb < 4; ++nb) acc[nb] = (f32x4){0.f, 0.f, 0.f, 0.f};

            #pragma unroll
            for (int ks = 0; ks < 16; ++ks) {
                const int feat = ((ks & 1) << 5) | (quad << 3);
                const int koff = (ks << 5) | (quad << 3);

                bf16x8 afr;
                size_t off = (size_t)idx[ks >> 1] * NODE_F + feat;
                if (A_BF16) {
                    afr = *(const bf16x8*)((const __bf16*)Asrc + off);
                } else {
                    const uint4* qp = (const uint4*)((const float*)Asrc + off);
                    uint4 a = qp[0], b = qp[1];
                    unsigned int v[8] = {a.x, a.y, a.z, a.w, b.x, b.y, b.z, b.w};
                    unsigned short* rp = (unsigned short*)&afr;
                    #pragma unroll
                    for (int i = 0; i < 8; ++i) rp[i] = f32_to_bf16_rne(v[i]);
                }

                #pragma unroll
                for (int nb = 0; nb < 4; ++nb) {
                    int n = nb * 16 + m;
                    bf16x8 bfr = *(const bf16x8*)(&ldsW[n * IN_F + ((koff + 8 * n) & (IN_F - 1))]);
                    acc[nb] = __builtin_amdgcn_mfma_f32_16x16x32_bf16(afr, bfr, acc[nb], 0, 0, 0);
                }
            }

            #pragma unroll
            for (int nb = 0; nb < 4; ++nb)
                #pragma unroll
                for (int r = 0; r < 4; ++r)
                    sum[nb][r] += softplus_sh(acc[nb][r] + bias[nb]);
        }
    }

    // ---- merge perm quarters through LDS aliased onto ldsW ----
    __syncthreads();                         // all waves done reading ldsW
    float* mbuf = (float*)ldsW;              // [3 qslots][2 tslots][16 rows][stride 68]
    if (active && q > 0) {
        const int base = ((q - 1) * 2 + tslot) * 16;
        #pragma unroll
        for (int nb = 0; nb < 4; ++nb)
            #pragma unroll
            for (int r = 0; r < 4; ++r)
                mbuf[(base + quad * 4 + r) * 68 + nb * 16 + m] = sum[nb][r];
    }
    __syncthreads();
    if (active && q == 0) {
        #pragma unroll
        for (int nb = 0; nb < 4; ++nb)
            #pragma unroll
            for (int r = 0; r < 4; ++r) {
                const int row = quad * 4 + r;
                float v = sum[nb][r]
                        + mbuf[((0 * 2 + tslot) * 16 + row) * 68 + nb * 16 + m]
                        + mbuf[((1 * 2 + tslot) * 16 + row) * 68 + nb * 16 + m]
                        + mbuf[((2 * 2 + tslot) * 16 + row) * 68 + nb * 16 + m]
                        - 12.0f * LN2F;
                size_t pos = (size_t)(tile * 16 + row) * OUT_F + nb * 16 + m;
                if (IS_BF16) ((__bf16*)outv)[pos] = (__bf16)v;
                else         ((float*)outv)[pos]  = v;
            }
    }
}

extern "C" void kernel_launch(void* const* d_in, const int* in_sizes, int n_in,
                              void* d_out, int out_size, void* d_ws, size_t ws_size,
                              hipStream_t stream) {
    const void* X  = d_in[0];                // (50000, 64)
    const int*  NS = (const int*)d_in[1];    // (50000, 12, 8) int32
    const void* W  = d_in[2];                // (64, 512)
    const void* B  = d_in[3];                // (64,)
    int*  flag = (int*)d_ws;
    void* Xbf  = (void*)((char*)d_ws + 64);  // bf16 X copy (6.4 MB)

    const size_t need = 64 + (size_t)N_SITES * NODE_F * 2;
    const bool   conv = ws_size >= need;

    hipLaunchKernelGGL(detect_dtype, dim3(1), dim3(64), 0, stream,
                       (const unsigned short*)X, flag);

    dim3 grid((N_TILES + 1) / 2), block(512);   // 1563 blocks, 2 tiles each

    // bf16-data path: gather straight from X
    hipLaunchKernelGGL((lcnn_main<1, 1>), grid, block, 0, stream,
                       X, NS, W, B, d_out, flag);

    if (conv) {
        int nchunk = N_SITES * NODE_F / 8;
        hipLaunchKernelGGL(convert_x, dim3((nchunk + 255) / 256), dim3(256), 0,
                           stream, (const uint4*)X, (uint4*)Xbf, flag);
        hipLaunchKernelGGL((lcnn_main<0, 1>), grid, block, 0, stream,
                           Xbf, NS, W, B, d_out, flag);
    } else {
        hipLaunchKernelGGL((lcnn_main<0, 0>), grid, block, 0, stream,
                           X, NS, W, B, d_out, flag);
    }
}

// Round 6
// 390.273 us; speedup vs baseline: 1.5597x; 1.5597x over previous
//
#include <hip/hip_runtime.h>
#include <hip/hip_bf16.h>

#define N_SITES 50000
#define N_PERM  12
#define N_NEIGH 8
#define NODE_F  64
#define IN_F    512
#define OUT_F   64
#define N_TILES (N_SITES / 16)   // 3125 exact
#define LN2F    0.69314718055994530942f

typedef __bf16 bf16x8 __attribute__((ext_vector_type(8)));
typedef float  f32x4  __attribute__((ext_vector_type(4)));

__device__ __forceinline__ unsigned short f32_to_bf16_rne(unsigned int u) {
    u += 0x7FFFu + ((u >> 16) & 1u);
    return (unsigned short)(u >> 16);
}

// Block-local dtype probe: every wave reads the SAME 64 even u16 slots of X.
// bf16 data -> exponents cluster near 127 (>=48 of 64 hit window); fp32 data
// read as u16 puts mantissa bits there (~12% hit). Uniform across the block,
// so using it to early-return is barrier-safe.
__device__ __forceinline__ int probe_is_bf16(const void* Xorig) {
    int lane = threadIdx.x & 63;
    unsigned short h = ((const unsigned short*)Xorig)[2 * lane];
    int e = (h >> 7) & 0xFF;
    unsigned long long mm = __ballot(e >= 110 && e <= 140);
    return (__popcll(mm) >= 48) ? 1 : 0;
}

// ---- X fp32 -> bf16 into workspace (self-detecting; no-op on bf16 data) ---
__global__ void convert_x(const uint4* __restrict__ Xf, uint4* __restrict__ Xb) {
    if (probe_is_bf16(Xf)) return;
    int c = blockIdx.x * blockDim.x + threadIdx.x;   // chunk of 8 floats
    if (c >= N_SITES * NODE_F / 8) return;
    uint4 a = Xf[2 * c], b = Xf[2 * c + 1];
    uint4 o;
    o.x = (unsigned int)f32_to_bf16_rne(a.x) | ((unsigned int)f32_to_bf16_rne(a.y) << 16);
    o.y = (unsigned int)f32_to_bf16_rne(a.z) | ((unsigned int)f32_to_bf16_rne(a.w) << 16);
    o.z = (unsigned int)f32_to_bf16_rne(b.x) | ((unsigned int)f32_to_bf16_rne(b.y) << 16);
    o.w = (unsigned int)f32_to_bf16_rne(b.z) | ((unsigned int)f32_to_bf16_rne(b.w) << 16);
    Xb[c] = o;
}

__device__ __forceinline__ float softplus_sh(float x) {
    float t = __expf(-fabsf(x));
    return fmaxf(x, 0.f) + 0.69314718056f * __log2f(1.f + t);
}

// R3 shape (wave = 16-site tile, all 12 perms, best measured point) with:
//  (a) __launch_bounds__(512,2): ~512-reg budget. LDS (64 KiB) already caps
//      occupancy at 2 blocks/CU = 16 waves/CU, so no occupancy loss.
//  (b) Deep MLP: per 2-perm group, ALL 32 A-fragments (16 B each) are loaded
//      into registers up-front (32 global_load_dwordx4 in flight per wave),
//      next group's indices prefetched -> Little's-law BW instead of
//      2-loads-then-stall. Dur tracked bytes at ~3.6 GB/us in R3-R5; this
//      attacks the latency side and keeps the byte count minimal.
// W (64x512 bf16) in LDS, rows rotated 8*o halves -> conflict-free (R2-R5).
template<int IS_BF16, int A_BF16>
__global__ __launch_bounds__(512, 2)
void lcnn_main(const void* __restrict__ Xorig, const void* __restrict__ Asrc,
               const int* __restrict__ NS, const void* __restrict__ Wv,
               const void* __restrict__ Bv, void* __restrict__ outv)
{
    if (probe_is_bf16(Xorig) != IS_BF16) return;   // uniform, pre-barrier

    __shared__ __bf16 ldsW[OUT_F * IN_F];   // 64 KiB

    #pragma unroll
    for (int it = 0; it < 8; ++it) {
        int c   = it * 512 + threadIdx.x;   // chunk of 8 halves
        int o   = c >> 6;
        int kc  = (c & 63) << 3;
        int dst = o * IN_F + ((kc + 8 * o) & (IN_F - 1));
        if (IS_BF16) {
            *(uint4*)(&ldsW[dst]) = ((const uint4*)Wv)[c];
        } else {
            uint4 a = ((const uint4*)Wv)[2 * c];
            uint4 b = ((const uint4*)Wv)[2 * c + 1];
            uint4 o4;
            o4.x = (unsigned int)f32_to_bf16_rne(a.x) | ((unsigned int)f32_to_bf16_rne(a.y) << 16);
            o4.y = (unsigned int)f32_to_bf16_rne(a.z) | ((unsigned int)f32_to_bf16_rne(a.w) << 16);
            o4.z = (unsigned int)f32_to_bf16_rne(b.x) | ((unsigned int)f32_to_bf16_rne(b.y) << 16);
            o4.w = (unsigned int)f32_to_bf16_rne(b.z) | ((unsigned int)f32_to_bf16_rne(b.w) << 16);
            *(uint4*)(&ldsW[dst]) = o4;
        }
    }
    __syncthreads();

    const int wave = threadIdx.x >> 6;
    const int lane = threadIdx.x & 63;
    const int tile = blockIdx.x * 8 + wave;
    if (tile >= N_TILES) return;            // after the only barrier

    const int m    = lane & 15;
    const int quad = lane >> 4;
    const int site = tile * 16 + m;
    const __bf16* __restrict__ A8 = (const __bf16*)Asrc;

    float bias[4];
    #pragma unroll
    for (int nb = 0; nb < 4; ++nb) {
        int i = nb * 16 + m;
        bias[nb] = IS_BF16 ? (float)((const __bf16*)Bv)[i] : ((const float*)Bv)[i];
    }

    f32x4 sum[4];
    #pragma unroll
    for (int nb = 0; nb < 4; ++nb) sum[nb] = (f32x4){0.f, 0.f, 0.f, 0.f};

    const int4* nsbase = (const int4*)(NS + (size_t)site * (N_PERM * N_NEIGH));

    // group-0 indices
    int idx[2][8];
    #pragma unroll
    for (int pp = 0; pp < 2; ++pp) {
        int4 a0 = nsbase[pp * 2], a1 = nsbase[pp * 2 + 1];
        idx[pp][0] = a0.x; idx[pp][1] = a0.y; idx[pp][2] = a0.z; idx[pp][3] = a0.w;
        idx[pp][4] = a1.x; idx[pp][5] = a1.y; idx[pp][6] = a1.z; idx[pp][7] = a1.w;
    }

    for (int g = 0; g < 6; ++g) {
        // ---- issue ALL 32 A-fragment loads for this group ----
        uint4 Ab[2][16];
        #pragma unroll
        for (int j = 0; j < 16; ++j) {
            const int feat = ((j & 1) << 5) | (quad << 3);
            #pragma unroll
            for (int pp = 0; pp < 2; ++pp)
                Ab[pp][j] = *(const uint4*)(A8 + (size_t)idx[pp][j >> 1] * NODE_F + feat);
        }

        // ---- prefetch next group's indices while loads are in flight ----
        int nidx[2][8];
        if (g < 5) {
            #pragma unroll
            for (int pp = 0; pp < 2; ++pp) {
                int4 a0 = nsbase[(g + 1) * 4 + pp * 2];
                int4 a1 = nsbase[(g + 1) * 4 + pp * 2 + 1];
                nidx[pp][0] = a0.x; nidx[pp][1] = a0.y; nidx[pp][2] = a0.z; nidx[pp][3] = a0.w;
                nidx[pp][4] = a1.x; nidx[pp][5] = a1.y; nidx[pp][6] = a1.z; nidx[pp][7] = a1.w;
            }
        }

        f32x4 acc[2][4];
        #pragma unroll
        for (int pp = 0; pp < 2; ++pp)
            #pragma unroll
            for (int nb = 0; nb < 4; ++nb)
                acc[pp][nb] = (f32x4){0.f, 0.f, 0.f, 0.f};

        #pragma unroll
        for (int ks = 0; ks < 16; ++ks) {
            const int koff = (ks << 5) | (quad << 3);
            #pragma unroll
            for (int nb = 0; nb < 4; ++nb) {
                int n = nb * 16 + m;
                bf16x8 bfr = *(const bf16x8*)(&ldsW[n * IN_F + ((koff + 8 * n) & (IN_F - 1))]);
                acc[0][nb] = __builtin_amdgcn_mfma_f32_16x16x32_bf16(
                    *(const bf16x8*)&Ab[0][ks], bfr, acc[0][nb], 0, 0, 0);
                acc[1][nb] = __builtin_amdgcn_mfma_f32_16x16x32_bf16(
                    *(const bf16x8*)&Ab[1][ks], bfr, acc[1][nb], 0, 0, 0);
            }
        }

        #pragma unroll
        for (int pp = 0; pp < 2; ++pp)
            #pragma unroll
            for (int nb = 0; nb < 4; ++nb)
                #pragma unroll
                for (int r = 0; r < 4; ++r)
                    sum[nb][r] += softplus_sh(acc[pp][nb][r] + bias[nb]);

        if (g < 5) {
            #pragma unroll
            for (int pp = 0; pp < 2; ++pp)
                #pragma unroll
                for (int j = 0; j < 8; ++j)
                    idx[pp][j] = nidx[pp][j];
        }
    }

    // C layout: row = quad*4 + r (site), col = nb*16 + m (out feature)
    #pragma unroll
    for (int nb = 0; nb < 4; ++nb)
        #pragma unroll
        for (int r = 0; r < 4; ++r) {
            size_t pos = (size_t)(tile * 16 + quad * 4 + r) * OUT_F + nb * 16 + m;
            float v = sum[nb][r] - 12.0f * LN2F;
            if (IS_BF16) ((__bf16*)outv)[pos] = (__bf16)v;
            else         ((float*)outv)[pos]  = v;
        }
}

extern "C" void kernel_launch(void* const* d_in, const int* in_sizes, int n_in,
                              void* d_out, int out_size, void* d_ws, size_t ws_size,
                              hipStream_t stream) {
    const void* X  = d_in[0];                // (50000, 64)
    const int*  NS = (const int*)d_in[1];    // (50000, 12, 8) int32
    const void* W  = d_in[2];                // (64, 512)
    const void* B  = d_in[3];                // (64,)
    void* Xbf = d_ws;                        // bf16 X copy (6.4 MB)

    const size_t need = (size_t)N_SITES * NODE_F * 2;
    const bool   conv = ws_size >= need;

    dim3 grid((N_TILES + 7) / 8), block(512);   // 391 blocks, 8 tiles each

    // bf16-data path: gather straight from X (self-detects; no-op otherwise)
    hipLaunchKernelGGL((lcnn_main<1, 1>), grid, block, 0, stream,
                       X, X, NS, W, B, d_out);

    if (conv) {
        int nchunk = N_SITES * NODE_F / 8;
        hipLaunchKernelGGL(convert_x, dim3((nchunk + 255) / 256), dim3(256), 0,
                           stream, (const uint4*)X, (uint4*)Xbf);
        hipLaunchKernelGGL((lcnn_main<0, 1>), grid, block, 0, stream,
                           X, Xbf, NS, W, B, d_out);
    } else {
        hipLaunchKernelGGL((lcnn_main<0, 0>), grid, block, 0, stream,
                           X, X, NS, W, B, d_out);
    }
}

// Round 7
// 382.798 us; speedup vs baseline: 1.5901x; 1.0195x over previous
//
#include <hip/hip_runtime.h>
#include <hip/hip_bf16.h>

#define N_SITES 50000
#define N_PERM  12
#define N_NEIGH 8
#define NODE_F  64
#define IN_F    512
#define OUT_F   64
#define N_TILES (N_SITES / 16)   // 3125 exact
#define LN2F    0.69314718055994530942f

typedef __bf16 bf16x8 __attribute__((ext_vector_type(8)));
typedef float  f32x4  __attribute__((ext_vector_type(4)));

__device__ __forceinline__ unsigned short f32_to_bf16_rne(unsigned int u) {
    u += 0x7FFFu + ((u >> 16) & 1u);
    return (unsigned short)(u >> 16);
}

// Block-uniform dtype probe (barrier-safe): bf16 data -> exponent field of
// even u16 slots clusters near 127; fp32 data read as u16 puts mantissa bits
// there (~12% window hits). Proven R2-R6: live path is fp32 (probe=0).
__device__ __forceinline__ int probe_is_bf16(const void* Xorig) {
    int lane = threadIdx.x & 63;
    unsigned short h = ((const unsigned short*)Xorig)[2 * lane];
    int e = (h >> 7) & 0xFF;
    unsigned long long mm = __ballot(e >= 110 && e <= 140);
    return (__popcll(mm) >= 48) ? 1 : 0;
}

// ---- X fp32 -> bf16 into workspace (self-detecting; no-op on bf16 data) ---
__global__ void convert_x(const uint4* __restrict__ Xf, uint4* __restrict__ Xb) {
    if (probe_is_bf16(Xf)) return;
    int c = blockIdx.x * blockDim.x + threadIdx.x;   // chunk of 8 floats
    if (c >= N_SITES * NODE_F / 8) return;
    uint4 a = Xf[2 * c], b = Xf[2 * c + 1];
    uint4 o;
    o.x = (unsigned int)f32_to_bf16_rne(a.x) | ((unsigned int)f32_to_bf16_rne(a.y) << 16);
    o.y = (unsigned int)f32_to_bf16_rne(a.z) | ((unsigned int)f32_to_bf16_rne(a.w) << 16);
    o.z = (unsigned int)f32_to_bf16_rne(b.x) | ((unsigned int)f32_to_bf16_rne(b.y) << 16);
    o.w = (unsigned int)f32_to_bf16_rne(b.z) | ((unsigned int)f32_to_bf16_rne(b.w) << 16);
    Xb[c] = o;
}

__device__ __forceinline__ float softplus_sh(float x) {
    float t = __expf(-fabsf(x));
    return fmaxf(x, 0.f) + 0.69314718056f * __log2f(1.f + t);
}

// REGISTER ARITHMETIC (the R3-R6 lesson): 64 KiB W-LDS caps residency at
// 2 blocks/CU. With 256-thr blocks that is 8 waves/CU = 2 waves/SIMD, so
// __launch_bounds__(256,2) grants a 256-reg unified budget — Ab[2][16](128)
// + acc(32) + sum(16) + idx/addr fit WITHOUT scratch spills (R6: 128-reg cap
// -> Ab spilled -> 237 MB scratch traffic, WRITE 256 MB).
// Wave = one 16-site tile, all 12 perms in 6 groups of 2; per group all 32
// A-fragments issued up-front (32 global_load_dwordx4 in flight/wave ->
// ~256 outstanding gathers/CU), next group's indices prefetched under them.
// W (64x512 bf16) in LDS, rows rotated 8*o halves -> conflict-free.
template<int IS_BF16, int A_BF16>
__global__ __launch_bounds__(256, 2)
void lcnn_main(const void* __restrict__ Xorig, const void* __restrict__ Asrc,
               const int* __restrict__ NS, const void* __restrict__ Wv,
               const void* __restrict__ Bv, void* __restrict__ outv)
{
    if (probe_is_bf16(Xorig) != IS_BF16) return;   // uniform, pre-barrier

    __shared__ __bf16 ldsW[OUT_F * IN_F];   // 64 KiB

    #pragma unroll
    for (int it = 0; it < 16; ++it) {
        int c   = it * 256 + threadIdx.x;   // chunk of 8 halves
        int o   = c >> 6;
        int kc  = (c & 63) << 3;
        int dst = o * IN_F + ((kc + 8 * o) & (IN_F - 1));
        if (IS_BF16) {
            *(uint4*)(&ldsW[dst]) = ((const uint4*)Wv)[c];
        } else {
            uint4 a = ((const uint4*)Wv)[2 * c];
            uint4 b = ((const uint4*)Wv)[2 * c + 1];
            uint4 o4;
            o4.x = (unsigned int)f32_to_bf16_rne(a.x) | ((unsigned int)f32_to_bf16_rne(a.y) << 16);
            o4.y = (unsigned int)f32_to_bf16_rne(a.z) | ((unsigned int)f32_to_bf16_rne(a.w) << 16);
            o4.z = (unsigned int)f32_to_bf16_rne(b.x) | ((unsigned int)f32_to_bf16_rne(b.y) << 16);
            o4.w = (unsigned int)f32_to_bf16_rne(b.z) | ((unsigned int)f32_to_bf16_rne(b.w) << 16);
            *(uint4*)(&ldsW[dst]) = o4;
        }
    }
    __syncthreads();

    const int wave = threadIdx.x >> 6;
    const int lane = threadIdx.x & 63;
    const int tile = blockIdx.x * 4 + wave;
    if (tile >= N_TILES) return;            // after the only barrier

    const int m    = lane & 15;
    const int quad = lane >> 4;
    const int site = tile * 16 + m;
    const __bf16* __restrict__ A8 = (const __bf16*)Asrc;

    float bias[4];
    #pragma unroll
    for (int nb = 0; nb < 4; ++nb) {
        int i = nb * 16 + m;
        bias[nb] = IS_BF16 ? (float)((const __bf16*)Bv)[i] : ((const float*)Bv)[i];
    }

    f32x4 sum[4];
    #pragma unroll
    for (int nb = 0; nb < 4; ++nb) sum[nb] = (f32x4){0.f, 0.f, 0.f, 0.f};

    const int4* nsbase = (const int4*)(NS + (size_t)site * (N_PERM * N_NEIGH));

    int idx[2][8];
    #pragma unroll
    for (int pp = 0; pp < 2; ++pp) {
        int4 a0 = nsbase[pp * 2], a1 = nsbase[pp * 2 + 1];
        idx[pp][0] = a0.x; idx[pp][1] = a0.y; idx[pp][2] = a0.z; idx[pp][3] = a0.w;
        idx[pp][4] = a1.x; idx[pp][5] = a1.y; idx[pp][6] = a1.z; idx[pp][7] = a1.w;
    }

    for (int g = 0; g < 6; ++g) {
        // ---- issue ALL 32 A-fragment loads for this group ----
        uint4 Ab[2][16];
        #pragma unroll
        for (int j = 0; j < 16; ++j) {
            const int feat = ((j & 1) << 5) | (quad << 3);
            #pragma unroll
            for (int pp = 0; pp < 2; ++pp)
                Ab[pp][j] = *(const uint4*)(A8 + (size_t)idx[pp][j >> 1] * NODE_F + feat);
        }

        // ---- prefetch next group's indices while gathers are in flight ----
        int nidx[2][8];
        if (g < 5) {
            #pragma unroll
            for (int pp = 0; pp < 2; ++pp) {
                int4 a0 = nsbase[(g + 1) * 4 + pp * 2];
                int4 a1 = nsbase[(g + 1) * 4 + pp * 2 + 1];
                nidx[pp][0] = a0.x; nidx[pp][1] = a0.y; nidx[pp][2] = a0.z; nidx[pp][3] = a0.w;
                nidx[pp][4] = a1.x; nidx[pp][5] = a1.y; nidx[pp][6] = a1.z; nidx[pp][7] = a1.w;
            }
        }

        f32x4 acc[2][4];
        #pragma unroll
        for (int pp = 0; pp < 2; ++pp)
            #pragma unroll
            for (int nb = 0; nb < 4; ++nb)
                acc[pp][nb] = (f32x4){0.f, 0.f, 0.f, 0.f};

        #pragma unroll
        for (int ks = 0; ks < 16; ++ks) {
            const int koff = (ks << 5) | (quad << 3);
            #pragma unroll
            for (int nb = 0; nb < 4; ++nb) {
                int n = nb * 16 + m;
                bf16x8 bfr = *(const bf16x8*)(&ldsW[n * IN_F + ((koff + 8 * n) & (IN_F - 1))]);
                acc[0][nb] = __builtin_amdgcn_mfma_f32_16x16x32_bf16(
                    *(const bf16x8*)&Ab[0][ks], bfr, acc[0][nb], 0, 0, 0);
                acc[1][nb] = __builtin_amdgcn_mfma_f32_16x16x32_bf16(
                    *(const bf16x8*)&Ab[1][ks], bfr, acc[1][nb], 0, 0, 0);
            }
        }

        #pragma unroll
        for (int pp = 0; pp < 2; ++pp)
            #pragma unroll
            for (int nb = 0; nb < 4; ++nb)
                #pragma unroll
                for (int r = 0; r < 4; ++r)
                    sum[nb][r] += softplus_sh(acc[pp][nb][r] + bias[nb]);

        if (g < 5) {
            #pragma unroll
            for (int pp = 0; pp < 2; ++pp)
                #pragma unroll
                for (int j = 0; j < 8; ++j)
                    idx[pp][j] = nidx[pp][j];
        }
    }

    // C layout: row = quad*4 + r (site), col = nb*16 + m (out feature)
    #pragma unroll
    for (int nb = 0; nb < 4; ++nb)
        #pragma unroll
        for (int r = 0; r < 4; ++r) {
            size_t pos = (size_t)(tile * 16 + quad * 4 + r) * OUT_F + nb * 16 + m;
            float v = sum[nb][r] - 12.0f * LN2F;
            if (IS_BF16) ((__bf16*)outv)[pos] = (__bf16)v;
            else         ((float*)outv)[pos]  = v;
        }
}

extern "C" void kernel_launch(void* const* d_in, const int* in_sizes, int n_in,
                              void* d_out, int out_size, void* d_ws, size_t ws_size,
                              hipStream_t stream) {
    const void* X  = d_in[0];                // (50000, 64)
    const int*  NS = (const int*)d_in[1];    // (50000, 12, 8) int32
    const void* W  = d_in[2];                // (64, 512)
    const void* B  = d_in[3];                // (64,)
    void* Xbf = d_ws;                        // bf16 X copy (6.4 MB)

    const size_t need = (size_t)N_SITES * NODE_F * 2;
    const bool   conv = ws_size >= need;

    dim3 grid((N_TILES + 3) / 4), block(256);   // 782 blocks, 4 tiles each

    // bf16-data path: gather straight from X (self-detects; no-op otherwise)
    hipLaunchKernelGGL((lcnn_main<1, 1>), grid, block, 0, stream,
                       X, X, NS, W, B, d_out);

    if (conv) {
        int nchunk = N_SITES * NODE_F / 8;
        hipLaunchKernelGGL(convert_x, dim3((nchunk + 255) / 256), dim3(256), 0,
                           stream, (const uint4*)X, (uint4*)Xbf);
        hipLaunchKernelGGL((lcnn_main<0, 1>), grid, block, 0, stream,
                           X, Xbf, NS, W, B, d_out);
    } else {
        hipLaunchKernelGGL((lcnn_main<0, 0>), grid, block, 0, stream,
                           X, X, NS, W, B, d_out);
    }
}

// Round 8
// 210.316 us; speedup vs baseline: 2.8942x; 1.8201x over previous
//
#include <hip/hip_runtime.h>
#include <hip/hip_bf16.h>

#define N_SITES 50000
#define N_PERM  12
#define N_NEIGH 8
#define NODE_F  64
#define IN_F    512
#define OUT_F   64
#define N_TILES (N_SITES / 16)   // 3125 exact, one block per tile
#define LN2F    0.69314718055994530942f

typedef __bf16 bf16x8 __attribute__((ext_vector_type(8)));
typedef float  f32x4  __attribute__((ext_vector_type(4)));

__device__ __forceinline__ unsigned short f32_to_bf16_rne(unsigned int u) {
    u += 0x7FFFu + ((u >> 16) & 1u);
    return (unsigned short)(u >> 16);
}

// Block-uniform dtype probe (R2-R7 proven: live path is fp32 -> probe=0).
__device__ __forceinline__ int probe_is_bf16(const void* Xorig) {
    int lane = threadIdx.x & 63;
    unsigned short h = ((const unsigned short*)Xorig)[2 * lane];
    int e = (h >> 7) & 0xFF;
    unsigned long long mm = __ballot(e >= 110 && e <= 140);
    return (__popcll(mm) >= 48) ? 1 : 0;
}

__device__ __forceinline__ void pack8(const uint4* src, uint4* dst, int c) {
    uint4 a = src[2 * c], b = src[2 * c + 1];
    uint4 o;
    o.x = (unsigned int)f32_to_bf16_rne(a.x) | ((unsigned int)f32_to_bf16_rne(a.y) << 16);
    o.y = (unsigned int)f32_to_bf16_rne(a.z) | ((unsigned int)f32_to_bf16_rne(a.w) << 16);
    o.z = (unsigned int)f32_to_bf16_rne(b.x) | ((unsigned int)f32_to_bf16_rne(b.y) << 16);
    o.w = (unsigned int)f32_to_bf16_rne(b.z) | ((unsigned int)f32_to_bf16_rne(b.w) << 16);
    dst[c] = o;
}

#define XCHUNKS (N_SITES * NODE_F / 8)   // 400000
#define WCHUNKS (OUT_F * IN_F / 8)       // 4096

// X and W fp32 -> bf16 into workspace (self-detecting; no-op on bf16 data)
__global__ void convert_xw(const uint4* __restrict__ Xf, const uint4* __restrict__ Wf,
                           uint4* __restrict__ Xb, uint4* __restrict__ Wb) {
    if (probe_is_bf16(Xf)) return;
    int c = blockIdx.x * blockDim.x + threadIdx.x;
    if (c < XCHUNKS)                pack8(Xf, Xb, c);
    else if (c < XCHUNKS + WCHUNKS) pack8(Wf, Wb, c - XCHUNKS);
}

__device__ __forceinline__ float softplus_sh(float x) {
    float t = __expf(-fabsf(x));
    return fmaxf(x, 0.f) + 0.69314718056f * __log2f(1.f + t);
}

// async 16B global->LDS (no VGPR cost for in-flight data; dest = uniform
// base + lane*16 per m104/m108).
__device__ __forceinline__ void async16(const __bf16* g, __bf16* l) {
    __builtin_amdgcn_global_load_lds(
        (const __attribute__((address_space(1))) unsigned int*)g,
        (__attribute__((address_space(3))) unsigned int*)l, 16, 0, 0);
}

// Block = 1 tile (16 sites) x 4 waves; wave w owns out-features 16w..16w+15
// with its 16 W B-fragments resident in 64 VGPRs (no W LDS, no merge).
// Gathers flow global->LDS via async DMA (structurally spill-free), 8 KB
// half-perm chunks, double-buffered; __syncthreads' implicit vmcnt(0) drain
// is the producer-consumer sync. LDS = 16 KiB total.
template<int IS_BF16>
__global__ __launch_bounds__(256, 3)
void lcnn_dma(const void* __restrict__ Xorig, const __bf16* __restrict__ Xb,
              const int* __restrict__ NS, const __bf16* __restrict__ Wb,
              const void* __restrict__ Bv, void* __restrict__ outv)
{
    if (probe_is_bf16(Xorig) != IS_BF16) return;   // uniform, pre-barrier

    __shared__ __align__(16) __bf16 Abuf[2][8][512];   // 2 x 8 KiB

    const int wave = threadIdx.x >> 6;
    const int lane = threadIdx.x & 63;
    const int m    = lane & 15;
    const int quad = lane >> 4;
    const int tile = blockIdx.x;
    const int site = tile * 16 + m;

    // W fragments for this wave's out-block: B[k][n]: n=m -> row 16w+m,
    // k = ks*32 + quad*8 + j  (16 B contiguous per fragment)
    bf16x8 Wfrag[16];
    #pragma unroll
    for (int ks = 0; ks < 16; ++ks)
        Wfrag[ks] = *(const bf16x8*)(Wb + (size_t)(wave * 16 + m) * IN_F + ks * 32 + quad * 8);

    const float bias = IS_BF16 ? (float)((const __bf16*)Bv)[wave * 16 + m]
                               : ((const float*)Bv)[wave * 16 + m];

    const int* nsrow = NS + (size_t)site * (N_PERM * N_NEIGH);

    // wave w stages chunks {2w, 2w+1} of each half: neighbor n = 4h + w,
    // feat = quad*8 (+32 for the odd chunk)
    auto stage = [&](int nb_idx, int buf) {
        const __bf16* rb = Xb + (size_t)nb_idx * NODE_F + quad * 8;
        async16(rb,      &Abuf[buf][2 * wave][0]);
        async16(rb + 32, &Abuf[buf][2 * wave + 1][0]);
    };

    f32x4 sum = {0.f, 0.f, 0.f, 0.f};
    f32x4 acc = {0.f, 0.f, 0.f, 0.f};

    // prologue: perm 0 indices, stage h0 -> buf0
    int i_h0 = nsrow[wave];
    int i_h1 = nsrow[4 + wave];
    stage(i_h0, 0);
    __syncthreads();                          // drains DMA: buf0 ready

    for (int p = 0; p < N_PERM; ++p) {
        // ---- h0: stage h1->buf1 (flies under compute), compute buf0 ----
        stage(i_h1, 1);
        int in_h0 = 0, in_h1 = 0;
        if (p + 1 < N_PERM) in_h0 = nsrow[(p + 1) * 8 + wave];
        #pragma unroll
        for (int j = 0; j < 8; ++j) {
            bf16x8 afr = *(const bf16x8*)&Abuf[0][j][lane * 8];
            acc = __builtin_amdgcn_mfma_f32_16x16x32_bf16(afr, Wfrag[j], acc, 0, 0, 0);
        }
        __syncthreads();                      // buf1 ready; buf0 free

        // ---- h1: stage next perm h0->buf0, compute buf1 ----
        if (p + 1 < N_PERM) {
            stage(in_h0, 0);
            in_h1 = nsrow[(p + 1) * 8 + 4 + wave];
        }
        #pragma unroll
        for (int j = 0; j < 8; ++j) {
            bf16x8 afr = *(const bf16x8*)&Abuf[1][j][lane * 8];
            acc = __builtin_amdgcn_mfma_f32_16x16x32_bf16(afr, Wfrag[8 + j], acc, 0, 0, 0);
        }
        #pragma unroll
        for (int r = 0; r < 4; ++r) sum[r] += softplus_sh(acc[r] + bias);
        acc = (f32x4){0.f, 0.f, 0.f, 0.f};
        i_h0 = in_h0; i_h1 = in_h1;
        __syncthreads();                      // buf0 ready next iter; buf1 free
    }

    // C: row = quad*4 + r (site), col = m; out feature = 16*wave + m
    #pragma unroll
    for (int r = 0; r < 4; ++r) {
        size_t pos = (size_t)(tile * 16 + quad * 4 + r) * OUT_F + wave * 16 + m;
        float v = sum[r] - 12.0f * LN2F;
        if (IS_BF16) ((__bf16*)outv)[pos] = (__bf16)v;
        else         ((float*)outv)[pos]  = v;
    }
}

// Never-taken safety net (fp32 data, workspace too small): direct compute.
__global__ void lcnn_fallback(const float* __restrict__ X, const int* __restrict__ NS,
                              const float* __restrict__ W, const float* __restrict__ B,
                              float* __restrict__ out) {
    if (probe_is_bf16(X)) return;
    int t = blockIdx.x * blockDim.x + threadIdx.x;
    if (t >= N_SITES * OUT_F) return;
    int sitei = t >> 6, o = t & 63;
    const int* ns = NS + (size_t)sitei * 96;
    float s = 0.f;
    for (int p = 0; p < N_PERM; ++p) {
        float x = B[o];
        for (int n = 0; n < N_NEIGH; ++n) {
            const float* xr = X + (size_t)ns[p * 8 + n] * NODE_F;
            const float* wr = W + (size_t)o * IN_F + n * NODE_F;
            for (int f = 0; f < NODE_F; ++f) x += xr[f] * wr[f];
        }
        s += softplus_sh(x);
    }
    out[t] = s - 12.0f * LN2F;
}

extern "C" void kernel_launch(void* const* d_in, const int* in_sizes, int n_in,
                              void* d_out, int out_size, void* d_ws, size_t ws_size,
                              hipStream_t stream) {
    const void* X  = d_in[0];                // (50000, 64)
    const int*  NS = (const int*)d_in[1];    // (50000, 12, 8) int32
    const void* W  = d_in[2];                // (64, 512)
    const void* B  = d_in[3];                // (64,)

    char* ws  = (char*)d_ws;
    __bf16* Xbf = (__bf16*)ws;                               // 6.4 MB
    __bf16* Wbf = (__bf16*)(ws + (size_t)N_SITES * NODE_F * 2);  // 64 KB
    const bool conv = ws_size >= (size_t)N_SITES * NODE_F * 2 + (size_t)OUT_F * IN_F * 2;

    dim3 grid(N_TILES), block(256);

    // bf16-data path: inputs already bf16 (self-detects; no-op otherwise)
    hipLaunchKernelGGL((lcnn_dma<1>), grid, block, 0, stream,
                       X, (const __bf16*)X, NS, (const __bf16*)W, B, d_out);

    if (conv) {
        int nch = XCHUNKS + WCHUNKS;
        hipLaunchKernelGGL(convert_xw, dim3((nch + 255) / 256), dim3(256), 0, stream,
                           (const uint4*)X, (const uint4*)W, (uint4*)Xbf, (uint4*)Wbf);
        hipLaunchKernelGGL((lcnn_dma<0>), grid, block, 0, stream,
                           X, Xbf, NS, Wbf, B, d_out);
    } else {
        hipLaunchKernelGGL(lcnn_fallback,
                           dim3((N_SITES * OUT_F + 255) / 256), dim3(256), 0, stream,
                           (const float*)X, NS, (const float*)W, (const float*)B,
                           (float*)d_out);
    }
}

// Round 9
// 144.340 us; speedup vs baseline: 4.2171x; 1.4571x over previous
//
#include <hip/hip_runtime.h>
#include <hip/hip_bf16.h>

#define N_SITES 50000
#define N_PERM  12
#define N_NEIGH 8
#define NODE_F  64
#define IN_F    512
#define OUT_F   64
#define N_TILES (N_SITES / 16)   // 3125 exact, one block per tile
#define LN2F    0.69314718055994530942f

#define XCHUNKS (N_SITES * NODE_F / 8)   // 400000 (16B bf16 chunks)
#define WCHUNKS (OUT_F * IN_F / 8)       // 4096
// per-perm staging: 16 DMA slots x (8 rows x 128 B + 16 B pad) = 16640 B
#define SLOT_E  520                       // bf16 elems per slot (1040 B)
#define BUF_E   (16 * SLOT_E)             // 8320 elems = 16640 B

typedef __bf16 bf16x8 __attribute__((ext_vector_type(8)));
typedef float  f32x4  __attribute__((ext_vector_type(4)));

__device__ __forceinline__ unsigned short f32_to_bf16_rne(unsigned int u) {
    u += 0x7FFFu + ((u >> 16) & 1u);
    return (unsigned short)(u >> 16);
}

// Block-uniform dtype probe (R2-R8 proven: live path is fp32 -> 0).
__device__ __forceinline__ int probe_is_bf16(const void* Xorig) {
    int lane = threadIdx.x & 63;
    unsigned short h = ((const unsigned short*)Xorig)[2 * lane];
    int e = (h >> 7) & 0xFF;
    unsigned long long mm = __ballot(e >= 110 && e <= 140);
    return (__popcll(mm) >= 48) ? 1 : 0;
}

__device__ __forceinline__ void pack8(const uint4* src, uint4* dst, int c) {
    uint4 a = src[2 * c], b = src[2 * c + 1];
    uint4 o;
    o.x = (unsigned int)f32_to_bf16_rne(a.x) | ((unsigned int)f32_to_bf16_rne(a.y) << 16);
    o.y = (unsigned int)f32_to_bf16_rne(a.z) | ((unsigned int)f32_to_bf16_rne(a.w) << 16);
    o.z = (unsigned int)f32_to_bf16_rne(b.x) | ((unsigned int)f32_to_bf16_rne(b.y) << 16);
    o.w = (unsigned int)f32_to_bf16_rne(b.z) | ((unsigned int)f32_to_bf16_rne(b.w) << 16);
    dst[c] = o;
}

// One kernel converts X, W (fp32->bf16, or plain copy if already bf16) and
// bias (->f32) into the workspace. Dtype-agnostic main kernel follows.
__global__ void convert_all(const void* __restrict__ Xv, const void* __restrict__ Wv,
                            const void* __restrict__ Bv, uint4* __restrict__ Xb,
                            uint4* __restrict__ Wb, float* __restrict__ Bf) {
    const int isbf = probe_is_bf16(Xv);
    int c = blockIdx.x * blockDim.x + threadIdx.x;
    if (c < XCHUNKS) {
        if (isbf) Xb[c] = ((const uint4*)Xv)[c];
        else      pack8((const uint4*)Xv, Xb, c);
    } else if (c < XCHUNKS + WCHUNKS) {
        int cw = c - XCHUNKS;
        if (isbf) Wb[cw] = ((const uint4*)Wv)[cw];
        else      pack8((const uint4*)Wv, Wb, cw);
    } else if (c < XCHUNKS + WCHUNKS + OUT_F) {
        int i = c - XCHUNKS - WCHUNKS;
        Bf[i] = isbf ? (float)((const __bf16*)Bv)[i] : ((const float*)Bv)[i];
    }
}

__device__ __forceinline__ float softplus_sh(float x) {
    float t = __expf(-fabsf(x));
    return fmaxf(x, 0.f) + 0.69314718056f * __log2f(1.f + t);
}

__device__ __forceinline__ void async16(const __bf16* g, __bf16* l) {
    __builtin_amdgcn_global_load_lds(
        (const __attribute__((address_space(1))) unsigned int*)g,
        (__attribute__((address_space(3))) unsigned int*)l, 16, 0, 0);
}

// Block = 1 tile (16 sites) x 4 waves; wave w owns out-features 16w..16w+15
// (16 W B-fragments in 64 VGPRs; no W LDS, no merge). Phase = ONE PERM:
// 16 DMA insts stage the full 16 KB A-tile; each inst's 8-lane groups fetch
// ONE FULL 128 B neighbor row -> 4.8M x 128 B L2 requests (R8 issued 9.6M x
// 64 B and plateaued at 4.3 TB/s effective = request-rate wall). Chunk XOR
// swizzle (c ^ lane>>3) + 16 B/slot pad keep ds_read_b128 <=2-way (free).
// Lag-1 double buffer: stage(p+1) flies under compute(p) (~400 cyc: ~RTT),
// one __syncthreads per perm (12 vs R8's 24 drains).
__global__ __launch_bounds__(256, 2)
void lcnn_dma(const void* __restrict__ Xorig, const __bf16* __restrict__ Xb,
              const int* __restrict__ NS, const __bf16* __restrict__ Wb,
              const float* __restrict__ Bf, void* __restrict__ outv)
{
    __shared__ __align__(16) __bf16 Abuf[2][BUF_E];   // 2 x 16640 B

    const int wave = threadIdx.x >> 6;
    const int lane = threadIdx.x & 63;
    const int m    = lane & 15;
    const int quad = lane >> 4;
    const int mk   = m & 7;
    const int mh   = m >> 3;
    const int tile = blockIdx.x;

    // W fragments: B[k][n] with n = 16w+m, k = ks*32 + quad*8 + j
    bf16x8 Wfrag[16];
    #pragma unroll
    for (int ks = 0; ks < 16; ++ks)
        Wfrag[ks] = *(const bf16x8*)(Wb + (size_t)(wave * 16 + m) * IN_F + ks * 32 + quad * 8);

    const float bias = Bf[wave * 16 + m];

    // DMA slot t = wave*4 + i covers neighbor k = t>>1, sites ((t&1)<<3)+0..7.
    // lane: row-in-slot = lane>>3, source chunk = (lane&7) ^ (lane>>3).
    auto load_idx = [&](int p_, int out[4]) {
        #pragma unroll
        for (int i = 0; i < 4; ++i) {
            int t = wave * 4 + i;
            int s = ((t & 1) << 3) + (lane >> 3);
            int k = t >> 1;
            out[i] = NS[(size_t)(tile * 16 + s) * (N_PERM * N_NEIGH) + p_ * N_NEIGH + k];
        }
    };
    auto stage = [&](int buf_, const int idxv[4]) {
        const int csrc = (lane & 7) ^ (lane >> 3);
        #pragma unroll
        for (int i = 0; i < 4; ++i) {
            int t = wave * 4 + i;
            async16(Xb + (size_t)idxv[i] * NODE_F + csrc * 8, &Abuf[buf_][t * SLOT_E]);
        }
    };

    int idxn[4];
    load_idx(0, idxn);
    stage(0, idxn);
    load_idx(1, idxn);
    __syncthreads();                          // buf0 staged (drains DMA)

    f32x4 sum = {0.f, 0.f, 0.f, 0.f};
    for (int p = 0; p < N_PERM; ++p) {
        if (p < N_PERM - 1) stage((p + 1) & 1, idxn);   // flies under compute
        if (p < N_PERM - 2) load_idx(p + 2, idxn);      // regs free post-issue

        f32x4 acc = {0.f, 0.f, 0.f, 0.f};
        const __bf16* bb = &Abuf[p & 1][0];
        #pragma unroll
        for (int ks = 0; ks < 16; ++ks) {
            // row r=(ks>>1)*16+m -> slot t=(ks>>1)*2+mh, in-slot row mk;
            // source chunk j=((ks&1)<<2)|quad lives at LDS chunk j^mk.
            int t_r = (ks >> 1) * 2 + mh;
            int j   = ((ks & 1) << 2) | quad;
            bf16x8 afr = *(const bf16x8*)(bb + t_r * SLOT_E + mk * 64 + ((j ^ mk) << 3));
            acc = __builtin_amdgcn_mfma_f32_16x16x32_bf16(afr, Wfrag[ks], acc, 0, 0, 0);
        }
        #pragma unroll
        for (int r = 0; r < 4; ++r) sum[r] += softplus_sh(acc[r] + bias);
        __syncthreads();                      // next buf ready; this buf free
    }

    // C: row = quad*4 + r (site), out feature = 16*wave + m (R8-proven)
    const int isbf = probe_is_bf16(Xorig);
    #pragma unroll
    for (int r = 0; r < 4; ++r) {
        size_t pos = (size_t)(tile * 16 + quad * 4 + r) * OUT_F + wave * 16 + m;
        float v = sum[r] - 12.0f * LN2F;
        if (isbf) ((__bf16*)outv)[pos] = (__bf16)v;
        else      ((float*)outv)[pos]  = v;
    }
}

// Safety net (workspace too small — never seen): direct fp32 compute.
__global__ void lcnn_fallback(const float* __restrict__ X, const int* __restrict__ NS,
                              const float* __restrict__ W, const float* __restrict__ B,
                              float* __restrict__ out) {
    int t = blockIdx.x * blockDim.x + threadIdx.x;
    if (t >= N_SITES * OUT_F) return;
    int sitei = t >> 6, o = t & 63;
    const int* ns = NS + (size_t)sitei * 96;
    float s = 0.f;
    for (int p = 0; p < N_PERM; ++p) {
        float x = B[o];
        for (int n = 0; n < N_NEIGH; ++n) {
            const float* xr = X + (size_t)ns[p * 8 + n] * NODE_F;
            const float* wr = W + (size_t)o * IN_F + n * NODE_F;
            for (int f = 0; f < NODE_F; ++f) x += xr[f] * wr[f];
        }
        s += softplus_sh(x);
    }
    out[t] = s - 12.0f * LN2F;
}

extern "C" void kernel_launch(void* const* d_in, const int* in_sizes, int n_in,
                              void* d_out, int out_size, void* d_ws, size_t ws_size,
                              hipStream_t stream) {
    const void* X  = d_in[0];                // (50000, 64)
    const int*  NS = (const int*)d_in[1];    // (50000, 12, 8) int32
    const void* W  = d_in[2];                // (64, 512)
    const void* B  = d_in[3];                // (64,)

    char* ws = (char*)d_ws;
    __bf16* Xb = (__bf16*)ws;                                     // 6.4 MB
    __bf16* Wb = (__bf16*)(ws + (size_t)XCHUNKS * 16);            // 64 KB
    float*  Bf = (float*)(ws + (size_t)(XCHUNKS + WCHUNKS) * 16); // 256 B
    const bool conv = ws_size >= (size_t)(XCHUNKS + WCHUNKS) * 16 + OUT_F * 4;

    if (conv) {
        int nch = XCHUNKS + WCHUNKS + OUT_F;
        hipLaunchKernelGGL(convert_all, dim3((nch + 255) / 256), dim3(256), 0, stream,
                           X, W, B, (uint4*)Xb, (uint4*)Wb, Bf);
        hipLaunchKernelGGL(lcnn_dma, dim3(N_TILES), dim3(256), 0, stream,
                           X, Xb, NS, Wb, Bf, d_out);
    } else {
        hipLaunchKernelGGL(lcnn_fallback,
                           dim3((N_SITES * OUT_F + 255) / 256), dim3(256), 0, stream,
                           (const float*)X, NS, (const float*)W, (const float*)B,
                           (float*)d_out);
    }
}